// Round 13
// baseline (373.342 us; speedup 1.0000x reference)
//
#include <hip/hip_runtime.h>
#include <math.h>

#define N_USERS 50000
#define N_ITEMS 50000
#define N_NODES 100000
#define N_NODES_PAD 100032
#define EMB 64
#define N_LAYERS 3
#define N_EDGES 1600000
#define BATCH 16384
#define REG_C 1e-05f
#define SLOPE 0.01f
#define EPS_C 1e-12f

// bucket sort: bucket = row >> 8 (256 rows per bucket)
#define NBUK 391                 // ceil(100000/256)
#define TILE_C 6144              // edges staged per block in k_bucket_scatter
#define SPK_MAX 4608             // per-bucket LDS capacity in k_bucket_sort

// val quantization: val in [0, 0.05) -> 15-bit fixed point packed above 17-bit col
#define VAL_ENC 655360.0f        // 32768 / 0.05
#define VAL_DEC (1.0f / 655360.0f)

#define INIT_BLOCKS ((N_NODES * EMB / 4 + 255) / 256)   // 6250
#define HISTO_BLOCKS 256
#define BFIN_BLOCKS (BATCH / 4)  // 4096 blocks, 4 batch elems each

typedef __attribute__((ext_vector_type(8))) short bf16x8;
typedef __attribute__((ext_vector_type(4))) float f32x4;

__device__ __forceinline__ unsigned short f2bf(float f) {
    unsigned int b = __float_as_uint(f);
    return (unsigned short)((b + 0x7fffu + ((b >> 16) & 1u)) >> 16);   // RNE
}
__device__ __forceinline__ unsigned int pack2bf(float a, float b) {
    return (unsigned int)f2bf(a) | ((unsigned int)f2bf(b) << 16);
}
__device__ __forceinline__ float bf2f(unsigned short v) {
    return __uint_as_float(((unsigned int)v) << 16);
}

// ---------------- fused: ego init (blocks < INIT_BLOCKS) + per-block bucket histograms ----------------
// Histo part writes PRIVATE per-block histograms (pure stores) -> no global
// memset, no global atomics. k_buk_scan sums the 256 partials.
__global__ __launch_bounds__(256) void k_init_histo(const float* __restrict__ u_emb,
                                                    const float* __restrict__ i_emb,
                                                    unsigned short* __restrict__ ego_bf,
                                                    const int* __restrict__ rows,
                                                    int* __restrict__ hist_parts) {
    if (blockIdx.x < INIT_BLOCKS) {
        int idx = blockIdx.x * 256 + threadIdx.x;   // float4 index
        const int n4 = N_NODES * EMB / 4;
        if (idx < n4) {
            const int u4 = N_USERS * EMB / 4;
            float4 v = (idx < u4) ? ((const float4*)u_emb)[idx]
                                  : ((const float4*)i_emb)[idx - u4];
            ushort4 h;
            h.x = f2bf(v.x); h.y = f2bf(v.y); h.z = f2bf(v.z); h.w = f2bf(v.w);
            *(ushort4*)&ego_bf[(size_t)idx * 4] = h;
        }
    } else {
        __shared__ int h[NBUK];
        for (int i = threadIdx.x; i < NBUK; i += 256) h[i] = 0;
        __syncthreads();
        int bid = blockIdx.x - INIT_BLOCKS;
        int stride = HISTO_BLOCKS * 256;
        for (int e = bid * 256 + threadIdx.x; e < N_EDGES; e += stride)
            atomicAdd(&h[rows[e] >> 8], 1);
        __syncthreads();
        for (int i = threadIdx.x; i < NBUK; i += 256)
            hist_parts[bid * NBUK + i] = h[i];
    }
}

// ---------------- sum partials + scan bucket bases; zero loss accumulators ----------------
__global__ __launch_bounds__(512) void k_buk_scan(const int* __restrict__ hist_parts,
                                                  int* __restrict__ bukbase,
                                                  int* __restrict__ bukcur,
                                                  float* __restrict__ gacc,
                                                  int* __restrict__ cnt) {
    __shared__ int s[512];
    int t = threadIdx.x;
    int v = 0;
    if (t < NBUK) {
        #pragma unroll 4
        for (int b = 0; b < HISTO_BLOCKS; ++b) v += hist_parts[b * NBUK + t];
    }
    s[t] = v;
    __syncthreads();
    for (int st = 1; st < 512; st <<= 1) {
        int a = (t >= st) ? s[t - st] : 0;
        __syncthreads();
        s[t] += a;
        __syncthreads();
    }
    if (t < NBUK) { bukbase[t] = s[t] - v; bukcur[t] = s[t] - v; }
    if (t == 0) bukbase[NBUK] = N_EDGES;
    if (t == 400) gacc[0] = 0.f;
    if (t == 401) gacc[1] = 0.f;
    if (t == 402) cnt[0] = 0;
}

// ---------------- LDS-staged bucket scatter (coalesced runs) ----------------
__global__ __launch_bounds__(512) void k_bucket_scatter(const int* __restrict__ rows,
                                                        const int* __restrict__ cols,
                                                        const float* __restrict__ vals,
                                                        int* __restrict__ bukcur,
                                                        uint2* __restrict__ bucketed) {
    __shared__ uint2 stage[TILE_C];
    __shared__ int hist[NBUK];
    __shared__ int lofs[NBUK];
    __shared__ int lcur[NBUK];
    __shared__ int gbase[NBUK];
    __shared__ int scan_s[512];
    int tid = threadIdx.x;
    int e0 = blockIdx.x * TILE_C;
    int n = min(TILE_C, N_EDGES - e0);

    for (int i = tid; i < NBUK; i += 512) hist[i] = 0;
    __syncthreads();
    for (int i = tid; i < n; i += 512) atomicAdd(&hist[rows[e0 + i] >> 8], 1);
    __syncthreads();
    // exclusive scan of hist
    int v = (tid < NBUK) ? hist[tid] : 0;
    scan_s[tid] = v;
    __syncthreads();
    for (int st = 1; st < 512; st <<= 1) {
        int a = (tid >= st) ? scan_s[tid - st] : 0;
        __syncthreads();
        scan_s[tid] += a;
        __syncthreads();
    }
    if (tid < NBUK) {
        int excl = scan_s[tid] - v;
        lofs[tid] = excl;
        lcur[tid] = excl;
        gbase[tid] = v ? atomicAdd(&bukcur[tid], v) : 0;   // one global atomic per bucket per block
    }
    __syncthreads();
    // bin edges into LDS, bucket-grouped
    for (int i = tid; i < n; i += 512) {
        int e = e0 + i;
        int r = rows[e];
        unsigned int q = __float2uint_rn(vals[e] * VAL_ENC);
        q = (q > 32767u) ? 32767u : q;
        unsigned int pk = (unsigned int)cols[e] | (q << 17);
        int pos = atomicAdd(&lcur[r >> 8], 1);
        stage[pos] = make_uint2(pk, (unsigned int)r);
    }
    __syncthreads();
    // contiguous run writes: element i belongs to bucket stage[i].y>>8
    for (int i = tid; i < n; i += 512) {
        uint2 w = stage[i];
        int b = w.y >> 8;
        bucketed[gbase[b] + (i - lofs[b])] = w;
    }
}

// ---------------- within-bucket sort -> final CSR (edge_pk, offsets) ----------------
__global__ __launch_bounds__(256) void k_bucket_sort(const int* __restrict__ bukbase,
                                                     const uint2* __restrict__ bucketed,
                                                     unsigned int* __restrict__ edge_pk,
                                                     int* __restrict__ offsets) {
    __shared__ int hist[256];
    __shared__ int lofs[256];
    __shared__ int lcur[256];
    __shared__ unsigned int spk[SPK_MAX];
    int b = blockIdx.x, tid = threadIdx.x;
    int s = bukbase[b], e = bukbase[b + 1];
    int cnt = e - s;
    int r0 = b << 8;
    int nrows = min(256, N_NODES - r0);

    hist[tid] = 0;
    __syncthreads();
    for (int i = tid; i < cnt; i += 256) atomicAdd(&hist[bucketed[s + i].y & 255u], 1);
    __syncthreads();
    int v = hist[tid];
    lofs[tid] = v;
    __syncthreads();
    for (int st = 1; st < 256; st <<= 1) {
        int a = (tid >= st) ? lofs[tid - st] : 0;
        __syncthreads();
        lofs[tid] += a;
        __syncthreads();
    }
    int excl = lofs[tid] - v;   // own-element read only; no race
    __syncthreads();
    lofs[tid] = excl;
    lcur[tid] = excl;
    if (tid < nrows) offsets[r0 + tid] = s + excl;
    if (b == NBUK - 1 && tid == 0) offsets[N_NODES] = N_EDGES;
    __syncthreads();

    if (cnt <= SPK_MAX) {
        for (int i = tid; i < cnt; i += 256) {
            uint2 w = bucketed[s + i];
            int p = atomicAdd(&lcur[w.y & 255u], 1);
            spk[p] = w.x;
        }
        __syncthreads();
        for (int i = tid; i < cnt; i += 256) edge_pk[s + i] = spk[i];   // coalesced
    } else {
        // overflow fallback (statistically unreachable): direct global scatter
        for (int i = tid; i < cnt; i += 256) {
            uint2 w = bucketed[s + i];
            int p = atomicAdd(&lcur[w.y & 255u], 1);
            edge_pk[s + p] = w.x;
        }
    }
}

// ---------------- per-layer: gather-based segment sum (bf16 in, bf16 out) ----------------
// 2 nodes per wave, 50000 waves. Lane split: half = lane>>5 (node),
// g = (lane>>3)&3 (edge slot), h = lane&7 (16B slot of the 128B bf16 row).
// One global_load_dwordx4 serves 8 edges (1KB; each row = exactly 1 TCC line,
// the proven traffic floor — fp8 null experiment, R11). g==0 lanes pack ws.
__global__ __launch_bounds__(256) void k_edge_agg(const int* __restrict__ offsets,
                                                  const unsigned int* __restrict__ edge_pk,
                                                  const unsigned short* __restrict__ ego_in,
                                                  unsigned short* __restrict__ ws_bf) {
    int wid = blockIdx.x * 4 + (threadIdx.x >> 6);   // wave id: owns nodes 2w, 2w+1
    int lane = threadIdx.x & 63;
    int half = lane >> 5;
    int g = (lane >> 3) & 3;
    int h = lane & 7;
    int n = wid * 2 + half;
    if (n >= N_NODES) return;
    int o0 = offsets[n], o1 = offsets[n + 1];
    int T = (o1 - o0 + 3) >> 2;    // per-half bound; wave runs max via exec mask
    float a0 = 0.f, a1 = 0.f, a2 = 0.f, a3 = 0.f;
    float a4 = 0.f, a5 = 0.f, a6 = 0.f, a7 = 0.f;
    int e = o0 + g;
    unsigned int pk = (e < o1) ? edge_pk[e] : 0u;
    for (int t = 0; t < T; ++t) {
        unsigned int cur = pk;
        int en = e + 4;
        pk = (en < o1) ? edge_pk[en] : 0u;   // prefetch next meta
        int c = (int)(cur & 0x1FFFFu);
        float v = (float)(cur >> 17) * VAL_DEC;
        uint4 r = *(const uint4*)&ego_in[(size_t)c * EMB + h * 8];
        a0 += v * __uint_as_float(r.x << 16);
        a1 += v * __uint_as_float(r.x & 0xffff0000u);
        a2 += v * __uint_as_float(r.y << 16);
        a3 += v * __uint_as_float(r.y & 0xffff0000u);
        a4 += v * __uint_as_float(r.z << 16);
        a5 += v * __uint_as_float(r.z & 0xffff0000u);
        a6 += v * __uint_as_float(r.w << 16);
        a7 += v * __uint_as_float(r.w & 0xffff0000u);
        e = en;
    }
    // reduce over the 4 edge-groups (masks 8,16 stay inside each 32-lane half)
    a0 += __shfl_xor(a0, 8, 64);  a1 += __shfl_xor(a1, 8, 64);
    a2 += __shfl_xor(a2, 8, 64);  a3 += __shfl_xor(a3, 8, 64);
    a4 += __shfl_xor(a4, 8, 64);  a5 += __shfl_xor(a5, 8, 64);
    a6 += __shfl_xor(a6, 8, 64);  a7 += __shfl_xor(a7, 8, 64);
    a0 += __shfl_xor(a0, 16, 64); a1 += __shfl_xor(a1, 16, 64);
    a2 += __shfl_xor(a2, 16, 64); a3 += __shfl_xor(a3, 16, 64);
    a4 += __shfl_xor(a4, 16, 64); a5 += __shfl_xor(a5, 16, 64);
    a6 += __shfl_xor(a6, 16, 64); a7 += __shfl_xor(a7, 16, 64);
    if (g == 0) {
        uint4 o;
        o.x = pack2bf(a0, a1); o.y = pack2bf(a2, a3);
        o.z = pack2bf(a4, a5); o.w = pack2bf(a6, a7);
        *(uint4*)&ws_bf[(size_t)n * EMB + h * 8] = o;
    }
}

// ---------------- per-layer transform: MFMA bf16 GEMM (all-bf16 I/O) ----------------
// t = [ws | ws*ego] @ Wcat^T + b1 + b2 ; leaky -> bf16 ego_out (per-layer buffer).
// X staged in LDS bf16 with 16B-granular XOR swizzle; ws half is a raw copy.
__global__ __launch_bounds__(256) void k_transform(const unsigned short* __restrict__ ws_bf,
                                                   const unsigned short* __restrict__ ego_in,
                                                   unsigned short* __restrict__ ego_out,
                                                   const float* __restrict__ W1,
                                                   const float* __restrict__ b1,
                                                   const float* __restrict__ W2,
                                                   const float* __restrict__ b2) {
    __shared__ short Xs16[64 * 128];   // [row][kc ^ (row&7)] in 8-elem (16B) units
    __shared__ short Wb[16 * 64 * 8];  // [frag s*4+j][lane][8]
    int tid = threadIdx.x;
    int r0 = blockIdx.x * 64;

    // ---- stage W fragments: c = j*16 + (ln&15), k = s*32 + (ln>>4)*8 + i ----
    for (int u = tid; u < 1024; u += 256) {
        int fidx = u >> 6, ln = u & 63;
        int s = fidx >> 2, j = fidx & 3;
        int c = j * 16 + (ln & 15);
        int k = s * 32 + ((ln >> 4) << 3);
        const float* Wsrc = (k < 64) ? &W1[c * 64 + k] : &W2[c * 64 + (k - 64)];
        float4 wlo = *(const float4*)Wsrc;
        float4 whi = *(const float4*)(Wsrc + 4);
        uint4 o;
        o.x = pack2bf(wlo.x, wlo.y); o.y = pack2bf(wlo.z, wlo.w);
        o.z = pack2bf(whi.x, whi.y); o.w = pack2bf(whi.z, whi.w);
        *(uint4*)&Wb[u * 8] = o;
    }

    // ---- stage X = [ws | ws*ego] bf16, swizzled 16B units ----
    for (int u = tid; u < 1024; u += 256) {
        int row = u >> 4, kc = u & 15;          // kc<8 => ws (raw copy), else aff
        size_t gbase = (size_t)(r0 + row) * EMB + ((kc & 7) << 3);
        uint4 wsv = *(const uint4*)&ws_bf[gbase];
        uint4 o;
        if (kc < 8) {
            o = wsv;
        } else {
            uint4 eb = *(const uint4*)&ego_in[gbase];
            o.x = pack2bf(__uint_as_float(wsv.x << 16) * __uint_as_float(eb.x << 16),
                          __uint_as_float(wsv.x & 0xffff0000u) * __uint_as_float(eb.x & 0xffff0000u));
            o.y = pack2bf(__uint_as_float(wsv.y << 16) * __uint_as_float(eb.y << 16),
                          __uint_as_float(wsv.y & 0xffff0000u) * __uint_as_float(eb.y & 0xffff0000u));
            o.z = pack2bf(__uint_as_float(wsv.z << 16) * __uint_as_float(eb.z << 16),
                          __uint_as_float(wsv.z & 0xffff0000u) * __uint_as_float(eb.z & 0xffff0000u));
            o.w = pack2bf(__uint_as_float(wsv.w << 16) * __uint_as_float(eb.w << 16),
                          __uint_as_float(wsv.w & 0xffff0000u) * __uint_as_float(eb.w & 0xffff0000u));
        }
        *(uint4*)&Xs16[(row * 16 + (kc ^ (row & 7))) * 8] = o;
    }
    __syncthreads();

    // ---- MFMA: wave wv covers rows wv*16..+15, all 64 cols ----
    int l = tid & 63, wv = tid >> 6;
    int arow = wv * 16 + (l & 15);              // A row this lane carries
    f32x4 acc[4];
    #pragma unroll
    for (int j = 0; j < 4; ++j) acc[j] = (f32x4){0.f, 0.f, 0.f, 0.f};
    #pragma unroll
    for (int s = 0; s < 4; ++s) {
        bf16x8 af = *(const bf16x8*)&Xs16[(arow * 16 + ((s * 4 + (l >> 4)) ^ (l & 7))) * 8];
        #pragma unroll
        for (int j = 0; j < 4; ++j) {
            bf16x8 bfr = *(const bf16x8*)&Wb[((s * 4 + j) * 64 + l) * 8];
            acc[j] = __builtin_amdgcn_mfma_f32_16x16x32_bf16(af, bfr, acc[j], 0, 0, 0);
        }
    }

    // ---- epilogue: bias + leaky, write bf16 ego_out ----
    int orow = r0 + wv * 16 + ((l >> 4) << 2);  // + reg r
    int ocol = l & 15;
    #pragma unroll
    for (int j = 0; j < 4; ++j) {
        int col = j * 16 + ocol;
        float bias = b1[col] + b2[col];
        #pragma unroll
        for (int r = 0; r < 4; ++r) {
            float t = acc[j][r] + bias;
            float o = (t >= 0.f) ? t : SLOPE * t;
            ego_out[(size_t)(orow + r) * EMB + col] = f2bf(o);
        }
    }
}

// ---------------- fused batch loss + finalize (single dispatch) ----------------
// 4096 blocks x 4 waves; wave = 1 batch element across all 4 layer buffers.
// Block LDS-reduce -> one atomicAdd pair; last block (counter) writes out.
__global__ __launch_bounds__(256) void k_batch_fin(const unsigned short* __restrict__ e0,
                                                   const unsigned short* __restrict__ e1,
                                                   const unsigned short* __restrict__ e2,
                                                   const unsigned short* __restrict__ e3,
                                                   const int* __restrict__ u,
                                                   const int* __restrict__ ii,
                                                   const int* __restrict__ jj,
                                                   float* __restrict__ gacc,
                                                   int* __restrict__ cnt,
                                                   float* __restrict__ out) {
    __shared__ float sls[4], sl2[4];
    int wv = threadIdx.x >> 6;
    int lane = threadIdx.x & 63;
    int wid = blockIdx.x * 4 + wv;
    size_t ru = (size_t)u[wid] * EMB + lane;
    size_t rp = (size_t)(N_USERS + ii[wid]) * EMB + lane;
    size_t rn = (size_t)(N_USERS + jj[wid]) * EMB + lane;
    const unsigned short* srcs[4] = { e0, e1, e2, e3 };
    float dup_t = 0.f, dun_t = 0.f, l2_t = 0.f;
    #pragma unroll
    for (int s = 0; s < 4; ++s) {
        float eu = bf2f(srcs[s][ru]);
        float ep = bf2f(srcs[s][rp]);
        float en = bf2f(srcs[s][rn]);
        float d_up = eu * ep, d_un = eu * en;
        float s_u = eu * eu, s_p = ep * ep, s_n = en * en;
        #pragma unroll
        for (int m = 32; m > 0; m >>= 1) {
            d_up += __shfl_xor(d_up, m, 64);
            d_un += __shfl_xor(d_un, m, 64);
            s_u  += __shfl_xor(s_u,  m, 64);
            s_p  += __shfl_xor(s_p,  m, 64);
            s_n  += __shfl_xor(s_n,  m, 64);
        }
        if (s > 0) {
            float inu = 1.f / fmaxf(sqrtf(s_u), EPS_C);
            float inp = 1.f / fmaxf(sqrtf(s_p), EPS_C);
            float inn = 1.f / fmaxf(sqrtf(s_n), EPS_C);
            d_up *= inu * inp;
            d_un *= inu * inn;
            s_u *= inu * inu;
            s_p *= inp * inp;
            s_n *= inn * inn;
        }
        dup_t += d_up; dun_t += d_un; l2_t += s_u + s_p + s_n;
    }
    if (lane == 0) {
        float x = dup_t - dun_t;
        sls[wv] = fminf(x, 0.f) - log1pf(expf(-fabsf(x)));   // log_sigmoid(x)
        sl2[wv] = l2_t;
    }
    __syncthreads();
    if (threadIdx.x == 0) {
        float ls = sls[0] + sls[1] + sls[2] + sls[3];
        float l2 = sl2[0] + sl2[1] + sl2[2] + sl2[3];
        atomicAdd(&gacc[0], ls);
        atomicAdd(&gacc[1], l2);
        __threadfence();
        int old = atomicAdd(cnt, 1);
        if (old == BFIN_BLOCKS - 1) {
            float gls = *(volatile float*)&gacc[0];
            float gl2 = *(volatile float*)&gacc[1];
            out[0] = -gls / (float)BATCH + REG_C * (gl2 * 0.5f) / (float)BATCH;
        }
    }
}

extern "C" void kernel_launch(void* const* d_in, const int* in_sizes, int n_in,
                              void* d_out, int out_size, void* d_ws, size_t ws_size,
                              hipStream_t stream) {
    (void)in_sizes; (void)n_in; (void)out_size; (void)ws_size;
    const int*   u     = (const int*)d_in[0];
    const int*   ii    = (const int*)d_in[1];
    const int*   jj    = (const int*)d_in[2];
    const int*   rows  = (const int*)d_in[3];
    const int*   cols  = (const int*)d_in[4];
    const float* vals  = (const float*)d_in[5];
    const float* u_emb = (const float*)d_in[6];
    const float* i_emb = (const float*)d_in[7];
    const float* W1_w  = (const float*)d_in[8];
    const float* W1_b  = (const float*)d_in[9];
    const float* W2_w  = (const float*)d_in[10];
    const float* W2_b  = (const float*)d_in[11];
    float* out = (float*)d_out;

    // workspace carve-up (rows padded to N_NODES_PAD so transform tail needs no guards)
    char* p = (char*)d_ws;
    unsigned short* ego[N_LAYERS + 1];
    for (int k = 0; k <= N_LAYERS; ++k) {
        ego[k] = (unsigned short*)p; p += (size_t)N_NODES_PAD * EMB * 2;
    }
    unsigned short* ws_bf     = (unsigned short*)p; p += (size_t)N_NODES_PAD * EMB * 2;
    uint2*          bucketed  = (uint2*)p;          p += (size_t)N_EDGES * 8;
    unsigned int*   edge_pk   = (unsigned int*)p;   p += (size_t)N_EDGES * 4;
    int*   offsets    = (int*)p;    p += (size_t)(N_NODES + 1) * 4;
    int*   hist_parts = (int*)p;    p += (size_t)HISTO_BLOCKS * NBUK * 4;
    int*   bukbase    = (int*)p;    p += (size_t)(NBUK + 1) * 4;
    int*   bukcur     = (int*)p;    p += (size_t)NBUK * 4;
    float* gacc       = (float*)p;  p += 2 * 4;
    int*   cnt        = (int*)p;    p += 4;

    k_init_histo<<<INIT_BLOCKS + HISTO_BLOCKS, 256, 0, stream>>>(u_emb, i_emb, ego[0], rows, hist_parts);
    k_buk_scan<<<1, 512, 0, stream>>>(hist_parts, bukbase, bukcur, gacc, cnt);
    k_bucket_scatter<<<(N_EDGES + TILE_C - 1) / TILE_C, 512, 0, stream>>>(rows, cols, vals, bukcur, bucketed);
    k_bucket_sort<<<NBUK, 256, 0, stream>>>(bukbase, bucketed, edge_pk, offsets);

    for (int k = 0; k < N_LAYERS; ++k) {
        // 2 nodes per wave -> 50000 waves -> 12500 blocks
        k_edge_agg<<<(N_NODES / 2 + 3) / 4, 256, 0, stream>>>(offsets, edge_pk, ego[k], ws_bf);
        k_transform<<<(N_NODES + 63) / 64, 256, 0, stream>>>(ws_bf, ego[k], ego[k + 1],
                                              W1_w + k * 4096, W1_b + k * 64,
                                              W2_w + k * 4096, W2_b + k * 64);
    }
    k_batch_fin<<<BFIN_BLOCKS, 256, 0, stream>>>(ego[0], ego[1], ego[2], ego[3],
                                                 u, ii, jj, gacc, cnt, out);
}

// Round 14
// 238.786 us; speedup vs baseline: 1.5635x; 1.5635x over previous
//
#include <hip/hip_runtime.h>
#include <math.h>

#define N_USERS 50000
#define N_ITEMS 50000
#define N_NODES 100000
#define N_NODES_PAD 100032
#define EMB 64
#define N_LAYERS 3
#define N_EDGES 1600000
#define BATCH 16384
#define REG_C 1e-05f
#define SLOPE 0.01f
#define EPS_C 1e-12f

// bucket sort: bucket = row >> 8 (256 rows per bucket)
#define NBUK 391                 // ceil(100000/256)
#define TILE_C 6144              // edges staged per block in k_bucket_scatter
#define SPK_MAX 4608             // per-bucket LDS capacity in k_bucket_sort

// val quantization: val in [0, 0.05) -> 15-bit fixed point packed above 17-bit col
#define VAL_ENC 655360.0f        // 32768 / 0.05
#define VAL_DEC (1.0f / 655360.0f)

#define INIT_BLOCKS ((N_NODES * EMB / 4 + 255) / 256)   // 6250
#define HISTO_BLOCKS 256
#define BALL_BLOCKS (BATCH / 4)  // 4096 blocks, 4 batch elems each

typedef __attribute__((ext_vector_type(8))) short bf16x8;
typedef __attribute__((ext_vector_type(4))) float f32x4;

__device__ __forceinline__ unsigned short f2bf(float f) {
    unsigned int b = __float_as_uint(f);
    return (unsigned short)((b + 0x7fffu + ((b >> 16) & 1u)) >> 16);   // RNE
}
__device__ __forceinline__ unsigned int pack2bf(float a, float b) {
    return (unsigned int)f2bf(a) | ((unsigned int)f2bf(b) << 16);
}
__device__ __forceinline__ float bf2f(unsigned short v) {
    return __uint_as_float(((unsigned int)v) << 16);
}

// ---------------- fused: ego init (blocks < INIT_BLOCKS) + per-block bucket histograms ----------------
// Histo part writes PRIVATE per-block histograms (pure stores) -> no global
// memset, no global atomics. k_buk_scan sums the 256 partials.
__global__ __launch_bounds__(256) void k_init_histo(const float* __restrict__ u_emb,
                                                    const float* __restrict__ i_emb,
                                                    unsigned short* __restrict__ ego_bf,
                                                    const int* __restrict__ rows,
                                                    int* __restrict__ hist_parts) {
    if (blockIdx.x < INIT_BLOCKS) {
        int idx = blockIdx.x * 256 + threadIdx.x;   // float4 index
        const int n4 = N_NODES * EMB / 4;
        if (idx < n4) {
            const int u4 = N_USERS * EMB / 4;
            float4 v = (idx < u4) ? ((const float4*)u_emb)[idx]
                                  : ((const float4*)i_emb)[idx - u4];
            ushort4 h;
            h.x = f2bf(v.x); h.y = f2bf(v.y); h.z = f2bf(v.z); h.w = f2bf(v.w);
            *(ushort4*)&ego_bf[(size_t)idx * 4] = h;
        }
    } else {
        __shared__ int h[NBUK];
        for (int i = threadIdx.x; i < NBUK; i += 256) h[i] = 0;
        __syncthreads();
        int bid = blockIdx.x - INIT_BLOCKS;
        int stride = HISTO_BLOCKS * 256;
        for (int e = bid * 256 + threadIdx.x; e < N_EDGES; e += stride)
            atomicAdd(&h[rows[e] >> 8], 1);
        __syncthreads();
        for (int i = threadIdx.x; i < NBUK; i += 256)
            hist_parts[bid * NBUK + i] = h[i];
    }
}

// ---------------- sum partials + scan bucket bases ----------------
__global__ __launch_bounds__(512) void k_buk_scan(const int* __restrict__ hist_parts,
                                                  int* __restrict__ bukbase,
                                                  int* __restrict__ bukcur) {
    __shared__ int s[512];
    int t = threadIdx.x;
    int v = 0;
    if (t < NBUK) {
        #pragma unroll 4
        for (int b = 0; b < HISTO_BLOCKS; ++b) v += hist_parts[b * NBUK + t];
    }
    s[t] = v;
    __syncthreads();
    for (int st = 1; st < 512; st <<= 1) {
        int a = (t >= st) ? s[t - st] : 0;
        __syncthreads();
        s[t] += a;
        __syncthreads();
    }
    if (t < NBUK) { bukbase[t] = s[t] - v; bukcur[t] = s[t] - v; }
    if (t == 0) bukbase[NBUK] = N_EDGES;
}

// ---------------- LDS-staged bucket scatter (coalesced runs) ----------------
__global__ __launch_bounds__(512) void k_bucket_scatter(const int* __restrict__ rows,
                                                        const int* __restrict__ cols,
                                                        const float* __restrict__ vals,
                                                        int* __restrict__ bukcur,
                                                        uint2* __restrict__ bucketed) {
    __shared__ uint2 stage[TILE_C];
    __shared__ int hist[NBUK];
    __shared__ int lofs[NBUK];
    __shared__ int lcur[NBUK];
    __shared__ int gbase[NBUK];
    __shared__ int scan_s[512];
    int tid = threadIdx.x;
    int e0 = blockIdx.x * TILE_C;
    int n = min(TILE_C, N_EDGES - e0);

    for (int i = tid; i < NBUK; i += 512) hist[i] = 0;
    __syncthreads();
    for (int i = tid; i < n; i += 512) atomicAdd(&hist[rows[e0 + i] >> 8], 1);
    __syncthreads();
    // exclusive scan of hist
    int v = (tid < NBUK) ? hist[tid] : 0;
    scan_s[tid] = v;
    __syncthreads();
    for (int st = 1; st < 512; st <<= 1) {
        int a = (tid >= st) ? scan_s[tid - st] : 0;
        __syncthreads();
        scan_s[tid] += a;
        __syncthreads();
    }
    if (tid < NBUK) {
        int excl = scan_s[tid] - v;
        lofs[tid] = excl;
        lcur[tid] = excl;
        gbase[tid] = v ? atomicAdd(&bukcur[tid], v) : 0;   // one global atomic per bucket per block
    }
    __syncthreads();
    // bin edges into LDS, bucket-grouped
    for (int i = tid; i < n; i += 512) {
        int e = e0 + i;
        int r = rows[e];
        unsigned int q = __float2uint_rn(vals[e] * VAL_ENC);
        q = (q > 32767u) ? 32767u : q;
        unsigned int pk = (unsigned int)cols[e] | (q << 17);
        int pos = atomicAdd(&lcur[r >> 8], 1);
        stage[pos] = make_uint2(pk, (unsigned int)r);
    }
    __syncthreads();
    // contiguous run writes: element i belongs to bucket stage[i].y>>8
    for (int i = tid; i < n; i += 512) {
        uint2 w = stage[i];
        int b = w.y >> 8;
        bucketed[gbase[b] + (i - lofs[b])] = w;
    }
}

// ---------------- within-bucket sort -> final CSR (edge_pk, offsets) ----------------
__global__ __launch_bounds__(256) void k_bucket_sort(const int* __restrict__ bukbase,
                                                     const uint2* __restrict__ bucketed,
                                                     unsigned int* __restrict__ edge_pk,
                                                     int* __restrict__ offsets) {
    __shared__ int hist[256];
    __shared__ int lofs[256];
    __shared__ int lcur[256];
    __shared__ unsigned int spk[SPK_MAX];
    int b = blockIdx.x, tid = threadIdx.x;
    int s = bukbase[b], e = bukbase[b + 1];
    int cnt = e - s;
    int r0 = b << 8;
    int nrows = min(256, N_NODES - r0);

    hist[tid] = 0;
    __syncthreads();
    for (int i = tid; i < cnt; i += 256) atomicAdd(&hist[bucketed[s + i].y & 255u], 1);
    __syncthreads();
    int v = hist[tid];
    lofs[tid] = v;
    __syncthreads();
    for (int st = 1; st < 256; st <<= 1) {
        int a = (tid >= st) ? lofs[tid - st] : 0;
        __syncthreads();
        lofs[tid] += a;
        __syncthreads();
    }
    int excl = lofs[tid] - v;   // own-element read only; no race
    __syncthreads();
    lofs[tid] = excl;
    lcur[tid] = excl;
    if (tid < nrows) offsets[r0 + tid] = s + excl;
    if (b == NBUK - 1 && tid == 0) offsets[N_NODES] = N_EDGES;
    __syncthreads();

    if (cnt <= SPK_MAX) {
        for (int i = tid; i < cnt; i += 256) {
            uint2 w = bucketed[s + i];
            int p = atomicAdd(&lcur[w.y & 255u], 1);
            spk[p] = w.x;
        }
        __syncthreads();
        for (int i = tid; i < cnt; i += 256) edge_pk[s + i] = spk[i];   // coalesced
    } else {
        // overflow fallback (statistically unreachable): direct global scatter
        for (int i = tid; i < cnt; i += 256) {
            uint2 w = bucketed[s + i];
            int p = atomicAdd(&lcur[w.y & 255u], 1);
            edge_pk[s + p] = w.x;
        }
    }
}

// ---------------- per-layer: gather-based segment sum (bf16 in, bf16 out) ----------------
// 2 nodes per wave, 50000 waves. Lane split: half = lane>>5 (node),
// g = (lane>>3)&3 (edge slot), h = lane&7 (16B slot of the 128B bf16 row).
// One global_load_dwordx4 serves 8 edges (1KB; each row = exactly 1 TCC line,
// the proven traffic floor — fp8 null experiment, R11). g==0 lanes pack ws.
__global__ __launch_bounds__(256) void k_edge_agg(const int* __restrict__ offsets,
                                                  const unsigned int* __restrict__ edge_pk,
                                                  const unsigned short* __restrict__ ego_in,
                                                  unsigned short* __restrict__ ws_bf) {
    int wid = blockIdx.x * 4 + (threadIdx.x >> 6);   // wave id: owns nodes 2w, 2w+1
    int lane = threadIdx.x & 63;
    int half = lane >> 5;
    int g = (lane >> 3) & 3;
    int h = lane & 7;
    int n = wid * 2 + half;
    if (n >= N_NODES) return;
    int o0 = offsets[n], o1 = offsets[n + 1];
    int T = (o1 - o0 + 3) >> 2;    // per-half bound; wave runs max via exec mask
    float a0 = 0.f, a1 = 0.f, a2 = 0.f, a3 = 0.f;
    float a4 = 0.f, a5 = 0.f, a6 = 0.f, a7 = 0.f;
    int e = o0 + g;
    unsigned int pk = (e < o1) ? edge_pk[e] : 0u;
    for (int t = 0; t < T; ++t) {
        unsigned int cur = pk;
        int en = e + 4;
        pk = (en < o1) ? edge_pk[en] : 0u;   // prefetch next meta
        int c = (int)(cur & 0x1FFFFu);
        float v = (float)(cur >> 17) * VAL_DEC;
        uint4 r = *(const uint4*)&ego_in[(size_t)c * EMB + h * 8];
        a0 += v * __uint_as_float(r.x << 16);
        a1 += v * __uint_as_float(r.x & 0xffff0000u);
        a2 += v * __uint_as_float(r.y << 16);
        a3 += v * __uint_as_float(r.y & 0xffff0000u);
        a4 += v * __uint_as_float(r.z << 16);
        a5 += v * __uint_as_float(r.z & 0xffff0000u);
        a6 += v * __uint_as_float(r.w << 16);
        a7 += v * __uint_as_float(r.w & 0xffff0000u);
        e = en;
    }
    // reduce over the 4 edge-groups (masks 8,16 stay inside each 32-lane half)
    a0 += __shfl_xor(a0, 8, 64);  a1 += __shfl_xor(a1, 8, 64);
    a2 += __shfl_xor(a2, 8, 64);  a3 += __shfl_xor(a3, 8, 64);
    a4 += __shfl_xor(a4, 8, 64);  a5 += __shfl_xor(a5, 8, 64);
    a6 += __shfl_xor(a6, 8, 64);  a7 += __shfl_xor(a7, 8, 64);
    a0 += __shfl_xor(a0, 16, 64); a1 += __shfl_xor(a1, 16, 64);
    a2 += __shfl_xor(a2, 16, 64); a3 += __shfl_xor(a3, 16, 64);
    a4 += __shfl_xor(a4, 16, 64); a5 += __shfl_xor(a5, 16, 64);
    a6 += __shfl_xor(a6, 16, 64); a7 += __shfl_xor(a7, 16, 64);
    if (g == 0) {
        uint4 o;
        o.x = pack2bf(a0, a1); o.y = pack2bf(a2, a3);
        o.z = pack2bf(a4, a5); o.w = pack2bf(a6, a7);
        *(uint4*)&ws_bf[(size_t)n * EMB + h * 8] = o;
    }
}

// ---------------- per-layer transform: MFMA bf16 GEMM (all-bf16 I/O) ----------------
// t = [ws | ws*ego] @ Wcat^T + b1 + b2 ; leaky -> bf16 ego_out (per-layer buffer).
// X staged in LDS bf16 with 16B-granular XOR swizzle; ws half is a raw copy.
__global__ __launch_bounds__(256) void k_transform(const unsigned short* __restrict__ ws_bf,
                                                   const unsigned short* __restrict__ ego_in,
                                                   unsigned short* __restrict__ ego_out,
                                                   const float* __restrict__ W1,
                                                   const float* __restrict__ b1,
                                                   const float* __restrict__ W2,
                                                   const float* __restrict__ b2) {
    __shared__ short Xs16[64 * 128];   // [row][kc ^ (row&7)] in 8-elem (16B) units
    __shared__ short Wb[16 * 64 * 8];  // [frag s*4+j][lane][8]
    int tid = threadIdx.x;
    int r0 = blockIdx.x * 64;

    // ---- stage W fragments: c = j*16 + (ln&15), k = s*32 + (ln>>4)*8 + i ----
    for (int u = tid; u < 1024; u += 256) {
        int fidx = u >> 6, ln = u & 63;
        int s = fidx >> 2, j = fidx & 3;
        int c = j * 16 + (ln & 15);
        int k = s * 32 + ((ln >> 4) << 3);
        const float* Wsrc = (k < 64) ? &W1[c * 64 + k] : &W2[c * 64 + (k - 64)];
        float4 wlo = *(const float4*)Wsrc;
        float4 whi = *(const float4*)(Wsrc + 4);
        uint4 o;
        o.x = pack2bf(wlo.x, wlo.y); o.y = pack2bf(wlo.z, wlo.w);
        o.z = pack2bf(whi.x, whi.y); o.w = pack2bf(whi.z, whi.w);
        *(uint4*)&Wb[u * 8] = o;
    }

    // ---- stage X = [ws | ws*ego] bf16, swizzled 16B units ----
    for (int u = tid; u < 1024; u += 256) {
        int row = u >> 4, kc = u & 15;          // kc<8 => ws (raw copy), else aff
        size_t gbase = (size_t)(r0 + row) * EMB + ((kc & 7) << 3);
        uint4 wsv = *(const uint4*)&ws_bf[gbase];
        uint4 o;
        if (kc < 8) {
            o = wsv;
        } else {
            uint4 eb = *(const uint4*)&ego_in[gbase];
            o.x = pack2bf(__uint_as_float(wsv.x << 16) * __uint_as_float(eb.x << 16),
                          __uint_as_float(wsv.x & 0xffff0000u) * __uint_as_float(eb.x & 0xffff0000u));
            o.y = pack2bf(__uint_as_float(wsv.y << 16) * __uint_as_float(eb.y << 16),
                          __uint_as_float(wsv.y & 0xffff0000u) * __uint_as_float(eb.y & 0xffff0000u));
            o.z = pack2bf(__uint_as_float(wsv.z << 16) * __uint_as_float(eb.z << 16),
                          __uint_as_float(wsv.z & 0xffff0000u) * __uint_as_float(eb.z & 0xffff0000u));
            o.w = pack2bf(__uint_as_float(wsv.w << 16) * __uint_as_float(eb.w << 16),
                          __uint_as_float(wsv.w & 0xffff0000u) * __uint_as_float(eb.w & 0xffff0000u));
        }
        *(uint4*)&Xs16[(row * 16 + (kc ^ (row & 7))) * 8] = o;
    }
    __syncthreads();

    // ---- MFMA: wave wv covers rows wv*16..+15, all 64 cols ----
    int l = tid & 63, wv = tid >> 6;
    int arow = wv * 16 + (l & 15);              // A row this lane carries
    f32x4 acc[4];
    #pragma unroll
    for (int j = 0; j < 4; ++j) acc[j] = (f32x4){0.f, 0.f, 0.f, 0.f};
    #pragma unroll
    for (int s = 0; s < 4; ++s) {
        bf16x8 af = *(const bf16x8*)&Xs16[(arow * 16 + ((s * 4 + (l >> 4)) ^ (l & 7))) * 8];
        #pragma unroll
        for (int j = 0; j < 4; ++j) {
            bf16x8 bfr = *(const bf16x8*)&Wb[((s * 4 + j) * 64 + l) * 8];
            acc[j] = __builtin_amdgcn_mfma_f32_16x16x32_bf16(af, bfr, acc[j], 0, 0, 0);
        }
    }

    // ---- epilogue: bias + leaky, write bf16 ego_out ----
    int orow = r0 + wv * 16 + ((l >> 4) << 2);  // + reg r
    int ocol = l & 15;
    #pragma unroll
    for (int j = 0; j < 4; ++j) {
        int col = j * 16 + ocol;
        float bias = b1[col] + b2[col];
        #pragma unroll
        for (int r = 0; r < 4; ++r) {
            float t = acc[j][r] + bias;
            float o = (t >= 0.f) ? t : SLOPE * t;
            ego_out[(size_t)(orow + r) * EMB + col] = f2bf(o);
        }
    }
}

// ---------------- all-layers batch loss partials (contention-free stores) ----------------
// 4096 blocks x 4 waves; wave = 1 batch element across all 4 layer buffers.
// Block LDS-reduce -> ONE float2 STORE per block (no atomics).
__global__ __launch_bounds__(256) void k_batch_all(const unsigned short* __restrict__ e0,
                                                   const unsigned short* __restrict__ e1,
                                                   const unsigned short* __restrict__ e2,
                                                   const unsigned short* __restrict__ e3,
                                                   const int* __restrict__ u,
                                                   const int* __restrict__ ii,
                                                   const int* __restrict__ jj,
                                                   float2* __restrict__ bpart) {
    __shared__ float sls[4], sl2[4];
    int wv = threadIdx.x >> 6;
    int lane = threadIdx.x & 63;
    int wid = blockIdx.x * 4 + wv;
    size_t ru = (size_t)u[wid] * EMB + lane;
    size_t rp = (size_t)(N_USERS + ii[wid]) * EMB + lane;
    size_t rn = (size_t)(N_USERS + jj[wid]) * EMB + lane;
    const unsigned short* srcs[4] = { e0, e1, e2, e3 };
    float dup_t = 0.f, dun_t = 0.f, l2_t = 0.f;
    #pragma unroll
    for (int s = 0; s < 4; ++s) {
        float eu = bf2f(srcs[s][ru]);
        float ep = bf2f(srcs[s][rp]);
        float en = bf2f(srcs[s][rn]);
        float d_up = eu * ep, d_un = eu * en;
        float s_u = eu * eu, s_p = ep * ep, s_n = en * en;
        #pragma unroll
        for (int m = 32; m > 0; m >>= 1) {
            d_up += __shfl_xor(d_up, m, 64);
            d_un += __shfl_xor(d_un, m, 64);
            s_u  += __shfl_xor(s_u,  m, 64);
            s_p  += __shfl_xor(s_p,  m, 64);
            s_n  += __shfl_xor(s_n,  m, 64);
        }
        if (s > 0) {
            float inu = 1.f / fmaxf(sqrtf(s_u), EPS_C);
            float inp = 1.f / fmaxf(sqrtf(s_p), EPS_C);
            float inn = 1.f / fmaxf(sqrtf(s_n), EPS_C);
            d_up *= inu * inp;
            d_un *= inu * inn;
            s_u *= inu * inu;
            s_p *= inp * inp;
            s_n *= inn * inn;
        }
        dup_t += d_up; dun_t += d_un; l2_t += s_u + s_p + s_n;
    }
    if (lane == 0) {
        float x = dup_t - dun_t;
        sls[wv] = fminf(x, 0.f) - log1pf(expf(-fabsf(x)));   // log_sigmoid(x)
        sl2[wv] = l2_t;
    }
    __syncthreads();
    if (threadIdx.x == 0)
        bpart[blockIdx.x] = make_float2(sls[0] + sls[1] + sls[2] + sls[3],
                                        sl2[0] + sl2[1] + sl2[2] + sl2[3]);
}

// ---------------- final scalar: reduce 4096 block partials ----------------
__global__ __launch_bounds__(1024) void k_finalize(const float2* __restrict__ bpart,
                                                   float* __restrict__ out) {
    __shared__ float s1[1024], s2[1024];
    float ls = 0.f, l2 = 0.f;
    for (int b = threadIdx.x; b < BALL_BLOCKS; b += 1024) {
        float2 v = bpart[b];
        ls += v.x; l2 += v.y;
    }
    s1[threadIdx.x] = ls; s2[threadIdx.x] = l2;
    __syncthreads();
    for (int st = 512; st > 0; st >>= 1) {
        if ((int)threadIdx.x < st) {
            s1[threadIdx.x] += s1[threadIdx.x + st];
            s2[threadIdx.x] += s2[threadIdx.x + st];
        }
        __syncthreads();
    }
    if (threadIdx.x == 0)
        out[0] = -s1[0] / (float)BATCH + REG_C * (s2[0] * 0.5f) / (float)BATCH;
}

extern "C" void kernel_launch(void* const* d_in, const int* in_sizes, int n_in,
                              void* d_out, int out_size, void* d_ws, size_t ws_size,
                              hipStream_t stream) {
    (void)in_sizes; (void)n_in; (void)out_size; (void)ws_size;
    const int*   u     = (const int*)d_in[0];
    const int*   ii    = (const int*)d_in[1];
    const int*   jj    = (const int*)d_in[2];
    const int*   rows  = (const int*)d_in[3];
    const int*   cols  = (const int*)d_in[4];
    const float* vals  = (const float*)d_in[5];
    const float* u_emb = (const float*)d_in[6];
    const float* i_emb = (const float*)d_in[7];
    const float* W1_w  = (const float*)d_in[8];
    const float* W1_b  = (const float*)d_in[9];
    const float* W2_w  = (const float*)d_in[10];
    const float* W2_b  = (const float*)d_in[11];
    float* out = (float*)d_out;

    // workspace carve-up (rows padded to N_NODES_PAD so transform tail needs no guards)
    char* p = (char*)d_ws;
    unsigned short* ego[N_LAYERS + 1];
    for (int k = 0; k <= N_LAYERS; ++k) {
        ego[k] = (unsigned short*)p; p += (size_t)N_NODES_PAD * EMB * 2;
    }
    unsigned short* ws_bf     = (unsigned short*)p; p += (size_t)N_NODES_PAD * EMB * 2;
    uint2*          bucketed  = (uint2*)p;          p += (size_t)N_EDGES * 8;
    unsigned int*   edge_pk   = (unsigned int*)p;   p += (size_t)N_EDGES * 4;
    int*    offsets    = (int*)p;    p += (size_t)(N_NODES + 1) * 4;
    int*    hist_parts = (int*)p;    p += (size_t)HISTO_BLOCKS * NBUK * 4;
    int*    bukbase    = (int*)p;    p += (size_t)(NBUK + 1) * 4;
    int*    bukcur     = (int*)p;    p += (size_t)NBUK * 4;
    float2* bpart      = (float2*)p; p += (size_t)BALL_BLOCKS * 8;

    k_init_histo<<<INIT_BLOCKS + HISTO_BLOCKS, 256, 0, stream>>>(u_emb, i_emb, ego[0], rows, hist_parts);
    k_buk_scan<<<1, 512, 0, stream>>>(hist_parts, bukbase, bukcur);
    k_bucket_scatter<<<(N_EDGES + TILE_C - 1) / TILE_C, 512, 0, stream>>>(rows, cols, vals, bukcur, bucketed);
    k_bucket_sort<<<NBUK, 256, 0, stream>>>(bukbase, bucketed, edge_pk, offsets);

    for (int k = 0; k < N_LAYERS; ++k) {
        // 2 nodes per wave -> 50000 waves -> 12500 blocks
        k_edge_agg<<<(N_NODES / 2 + 3) / 4, 256, 0, stream>>>(offsets, edge_pk, ego[k], ws_bf);
        k_transform<<<(N_NODES + 63) / 64, 256, 0, stream>>>(ws_bf, ego[k], ego[k + 1],
                                              W1_w + k * 4096, W1_b + k * 64,
                                              W2_w + k * 4096, W2_b + k * 64);
    }
    k_batch_all<<<BALL_BLOCKS, 256, 0, stream>>>(ego[0], ego[1], ego[2], ego[3],
                                                 u, ii, jj, bpart);
    k_finalize<<<1, 1024, 0, stream>>>(bpart, out);
}